// Round 17
// baseline (72.024 us; speedup 1.0000x reference)
//
#include <hip/hip_runtime.h>
#include <stdint.h>

#define N_IMG 32
#define P_TOT 8400
#define NCLS 80
#define NMS_PRE 1000
#define MAXOUT 100
#define SCORE_THRF 0.01f
#define NMS_THRF 0.65f
#define CAND_N 2048
#define NB 512          // histogram bins over dk>>17
#define BINBASE 8192    // valid masked scores [0.01,1.0] -> dk>>17 in [8255,8686]
#define TIE_EPS 0.05f   // sigmoid float-rounding tie window (validated R9/R10/R12, absmax 0)

// Level layout: p in [0,6400): 80x80 s=8 ; [6400,8000): 40x40 s=16 ; [8000,8400): 20x20 s=32

__device__ __forceinline__ float sigmoidf_(float x) { return 1.0f / (1.0f + expf(-x)); }

// ---------------- Kernel 1: scores -> sort keys (R12/R16 exact — best measured) ----------------
__global__ __launch_bounds__(256) void k_score(
    const float* __restrict__ cls0, const float* __restrict__ cls1, const float* __restrict__ cls2,
    const float* __restrict__ obj0, const float* __restrict__ obj1, const float* __restrict__ obj2,
    uint64_t* __restrict__ keys)
{
    __shared__ float    pml[4][64];    // per-wave partial max logit
    __shared__ uint64_t part[4][64];   // per-wave partial packed sigmoid-argmax
    int lane = threadIdx.x & 63, wid = threadIdx.x >> 6;
    int a = blockIdx.x * 64 + lane;          // global anchor id, < 268800 exactly
    int n = a / P_TOT;
    int p = a - n * P_TOT;

    const float* cl; const float* ob; int HW, q;
    if (p < 6400)      { cl = cls0; ob = obj0; HW = 6400; q = p; }
    else if (p < 8000) { cl = cls1; ob = obj1; HW = 1600; q = p - 6400; }
    else               { cl = cls2; ob = obj2; HW = 400;  q = p - 8000; }

    const float* cbase = cl + (size_t)n * NCLS * HW + q;
    int c0 = wid * 20;

    float lg[20];
    #pragma unroll
    for (int i = 0; i < 20; ++i)
        lg[i] = cbase[(size_t)(c0 + i) * HW];
    __builtin_amdgcn_sched_group_barrier(0x20, 20, 0);   // 20 VMEM reads back-to-back

    float a0 = fmaxf(lg[0], lg[1]),  a1 = fmaxf(lg[2], lg[3]);
    float a2 = fmaxf(lg[4], lg[5]),  a3 = fmaxf(lg[6], lg[7]);
    float a4 = fmaxf(lg[8], lg[9]),  a5 = fmaxf(lg[10], lg[11]);
    float a6 = fmaxf(lg[12], lg[13]), a7 = fmaxf(lg[14], lg[15]);
    float a8 = fmaxf(lg[16], lg[17]), a9 = fmaxf(lg[18], lg[19]);
    float b0 = fmaxf(a0, a1), b1 = fmaxf(a2, a3), b2 = fmaxf(a4, a5);
    float b3 = fmaxf(a6, a7), b4 = fmaxf(a8, a9);
    float lmax = fmaxf(fmaxf(fmaxf(b0, b1), fmaxf(b2, b3)), b4);
    pml[wid][lane] = lmax;
    __syncthreads();

    float gmaxl = fmaxf(fmaxf(pml[0][lane], pml[1][lane]),
                        fmaxf(pml[2][lane], pml[3][lane]));
    float thr = gmaxl - TIE_EPS;
    uint64_t m = 0;
    #pragma unroll
    for (int i = 0; i < 20; ++i) {
        if (lg[i] >= thr) {
            float s = sigmoidf_(lg[i]);
            uint64_t pk = ((uint64_t)__float_as_uint(s) << 8) | (uint32_t)(79 - (c0 + i));
            m = m > pk ? m : pk;    // equal sig -> lower class wins (= jnp.argmax)
        }
    }
    part[wid][lane] = m;
    __syncthreads();

    if (wid == 0) {
        uint64_t m0 = part[0][lane], m1 = part[1][lane];
        uint64_t m2 = part[2][lane], m3 = part[3][lane];
        uint64_t ma = m0 > m1 ? m0 : m1, mb = m2 > m3 ? m2 : m3;
        uint64_t mm = ma > mb ? ma : mb;
        float best = __uint_as_float((uint32_t)(mm >> 8));   // = max_c sigmoid(cls_c), exact
        int bc = 79 - (int)(mm & 0xFFu);

        float so = sigmoidf_(ob[(size_t)n * HW + q]);
        float sc = __fmul_rn(best, so);
        float masked = (sc >= SCORE_THRF) ? sc : -1.0f;
        uint32_t u = __float_as_uint(masked);
        uint32_t ord = (u & 0x80000000u) ? ~u : (u | 0x80000000u);
        uint32_t dk = ~ord;                  // descending (valid => top bit 0)
        keys[a] = ((uint64_t)dk << 32) | (uint32_t)((p << 8) | bc);
    }
}

// ---------------- Kernel 2: select + decode + chunk-parallel NMS ----------------
__global__ __launch_bounds__(1024) void k_selnms(
    const uint64_t* __restrict__ keys,
    const float* __restrict__ reg0, const float* __restrict__ reg1, const float* __restrict__ reg2,
    float* __restrict__ out)
{
    __shared__ __align__(16) char big[55712];
    __shared__ int   s_misc[2];
    __shared__ float fsh[17];
    __shared__ int   kidx[MAXOUT];

    // select-phase overlays
    uint16_t* bin16   = (uint16_t*)big;                 // [8400]  (16800 B)
    uint32_t* hist    = (uint32_t*)(big + 16800);       // [512]
    uint32_t* base    = (uint32_t*)(big + 18848);       // [512]
    uint32_t* fill    = (uint32_t*)(big + 20896);       // [512]
    uint64_t* grouped = (uint64_t*)(big + 22944);       // [2048] (ends 39328)
    uint64_t* cand    = (uint64_t*)(big + 39328);       // [2048] (ends 55712)
    // nms-phase overlays (after decode; cand fully read before staging barrier)
    float4* s_obx = (float4*)big;                       // [1000] (16000)
    float*  s_oar = (float*) (big + 16000);             // [1000] ( 4000)
    float4* s_raw = (float4*)(big + 20000);             // [1000] (16000)
    float2* s_sl  = (float2*)(big + 36000);             // [1000] ( 8000) -> ends 44000

    int n = blockIdx.x, tid = threadIdx.x;
    const uint64_t* kbase = keys + (size_t)n * P_TOT;

    if (tid < NB) { hist[tid] = 0; fill[tid] = 0; }
    for (int t = tid; t < CAND_N; t += 1024) cand[t] = ~0ull;
    __syncthreads();

    // single global pass: histogram + cache (valid,bin) per key
    #pragma unroll
    for (int it = 0; it < 9; ++it) {
        int t = tid + it * 1024;
        if (t < P_TOT) {
            uint64_t k = kbase[t];
            uint32_t dk = (uint32_t)(k >> 32);
            uint16_t v = 0;
            if (!(dk & 0x80000000u)) {
                uint32_t bin = (dk >> 17) - BINBASE;
                atomicAdd(&hist[bin], 1u);
                v = (uint16_t)(bin + 1);
            }
            bin16[t] = v;
        }
    }
    __syncthreads();

    // wave-0 prefix over 512 bins: per-bin exclusive base, total, cutoff bin
    if (tid < 64) {
        uint32_t c[8]; uint32_t s = 0;
        #pragma unroll
        for (int i = 0; i < 8; ++i) { c[i] = hist[tid * 8 + i]; s += c[i]; }
        uint32_t inc = s;
        #pragma unroll
        for (int o = 1; o < 64; o <<= 1) {
            uint32_t v = __shfl_up(inc, o);
            if (tid >= o) inc += v;
        }
        uint32_t excl = inc - s;
        uint32_t b = excl;
        #pragma unroll
        for (int i = 0; i < 8; ++i) { base[tid * 8 + i] = b; b += c[i]; }
        uint32_t total = __shfl(inc, 63);
        uint32_t target = total < (uint32_t)NMS_PRE ? total : (uint32_t)NMS_PRE;
        uint32_t cum = excl; int found = 0x7fffffff;
        #pragma unroll
        for (int i = 0; i < 8; ++i) {
            cum += c[i];
            if (found == 0x7fffffff && cum >= target && target > 0) found = tid * 8 + i;
        }
        #pragma unroll
        for (int o = 32; o > 0; o >>= 1) { int f = __shfl_xor(found, o); found = f < found ? f : found; }
        if (tid == 0) { s_misc[0] = (total > 0) ? found : -1; s_misc[1] = (int)target; }
    }
    __syncthreads();
    int Bcut = s_misc[0];

    // scatter: LDS bin codes select candidates; full keys re-fetched (L2-hot) only for those
    #pragma unroll
    for (int it = 0; it < 9; ++it) {
        int t = tid + it * 1024;
        if (t < P_TOT) {
            uint16_t v = bin16[t];
            if (v != 0) {
                int bin = (int)v - 1;
                if (bin <= Bcut) {
                    uint32_t pos = base[bin] + atomicAdd(&fill[bin], 1u);
                    if (pos < CAND_N) grouped[pos] = kbase[t];
                }
            }
        }
    }
    __syncthreads();

    // exact rank within bin (keys unique -> total order identical to full sort)
    int ccnt = 0;
    if (Bcut >= 0) {
        uint32_t cc = base[Bcut] + hist[Bcut];
        ccnt = cc < (uint32_t)CAND_N ? (int)cc : CAND_N;
    }
    for (int s = tid; s < ccnt; s += 1024) {
        uint64_t k = grouped[s];
        uint32_t dk = (uint32_t)(k >> 32);
        int bin = (int)((dk >> 17) - BINBASE);
        uint32_t b0 = base[bin];
        uint32_t e0 = b0 + hist[bin]; if (e0 > (uint32_t)CAND_N) e0 = CAND_N;
        uint32_t r = b0;
        for (uint32_t t = b0; t < e0; ++t) r += (grouped[t] < k) ? 1u : 0u;
        if (r < (uint32_t)CAND_N) cand[r] = k;
    }
    int V = s_misc[1];
    __syncthreads();          // ranking done

    // decode top-1000 from cand (LDS) exactly like reference; 1 anchor per thread
    float4 bx = make_float4(0.f, 0.f, 0.f, 0.f);
    float scm = -1.0f, labf = 0.f, m = 0.f;
    if (tid < NMS_PRE) {
        uint64_t key = cand[tid];
        uint32_t dk = (uint32_t)(key >> 32);
        if (!(dk & 0x80000000u)) {
            uint32_t low = (uint32_t)key;
            int lab = (int)(low & 0xFFu);
            int p   = (int)(low >> 8);
            uint32_t ord = ~dk;
            scm = __uint_as_float(ord ^ 0x80000000u);   // valid => positive float

            const float* rg; int HW, q, W; float s;
            if (p < 6400)      { rg = reg0; HW = 6400; q = p;        W = 80; s = 8.f; }
            else if (p < 8000) { rg = reg1; HW = 1600; q = p - 6400; W = 40; s = 16.f; }
            else               { rg = reg2; HW = 400;  q = p - 8000; W = 20; s = 32.f; }

            float px = (float)(q % W) * s;   // exact
            float py = (float)(q / W) * s;   // exact
            const float* rb = rg + (size_t)n * 4 * HW + q;
            float dx = rb[0], dy = rb[HW], dw = rb[2 * HW], dh = rb[3 * HW];
            float cx = __fadd_rn(__fmul_rn(dx, s), px);
            float cy = __fadd_rn(__fmul_rn(dy, s), py);
            float hw = __fmul_rn(__fmul_rn(expf(dw), s), 0.5f);
            float hh = __fmul_rn(__fmul_rn(expf(dh), s), 0.5f);
            bx.x = __fsub_rn(cx, hw); bx.y = __fsub_rn(cy, hh);
            bx.z = __fadd_rn(cx, hw); bx.w = __fadd_rn(cy, hh);
            labf = (float)lab;
            m = fmaxf(fmaxf(fabsf(bx.x), fabsf(bx.y)), fmaxf(fabsf(bx.z), fabsf(bx.w)));
        }
    }

    // gmax = max|b| over the 1000 gathered boxes (16-wave reduce)
    #pragma unroll
    for (int o = 32; o > 0; o >>= 1) m = fmaxf(m, __shfl_xor(m, o));
    if ((tid & 63) == 0) fsh[tid >> 6] = m;
    __syncthreads();
    if (tid == 0) {
        float g = fsh[0];
        #pragma unroll
        for (int w = 1; w < 16; ++w) g = fmaxf(g, fsh[w]);
        fsh[16] = g;
    }
    __syncthreads();          // all cand reads complete before overlay below
    float gmax = fsh[16];

    // stage NMS arrays (overlays select region incl. start of cand — safe post-barrier)
    if (tid < NMS_PRE) {
        float off = __fmul_rn(labf, __fadd_rn(gmax, 1.0f)); // lab * (max|b| + 1)
        float x1 = __fadd_rn(bx.x, off), y1 = __fadd_rn(bx.y, off);
        float x2 = __fadd_rn(bx.z, off), y2 = __fadd_rn(bx.w, off);
        s_obx[tid] = make_float4(x1, y1, x2, y2);
        s_oar[tid] = __fmul_rn(__fsub_rn(x2, x1), __fsub_rn(y2, y1));
        s_raw[tid] = bx;
        s_sl[tid]  = make_float2(scm, labf);
    }
    __syncthreads();
    if (tid >= 64) return;      // wave 0 finishes alone

    // ---- greedy NMS, chunk-parallel (R4-validated decisions): lane owns candidate c*64+lane.
    // Catch-up: independent iterations over kept rows, ONE ballot per chunk.
    // In-chunk: suppressed bits cost ~4 cy; only kept bits pay the shfl+ballot round.
    int lane = tid;
    int count = 0;
    int nchunk = (V + 63) >> 6;
    for (int c = 0; c < nchunk && count < MAXOUT; ++c) {
        int jcol = (c << 6) + lane;
        bool colv = jcol < V;
        int jsafe = colv ? jcol : 0;
        float4 bj = s_obx[jsafe];
        float  aj = s_oar[jsafe];

        // catch-up: test own candidate against all currently-kept boxes (prior chunks)
        bool sup0 = false;
        for (int mm = 0; mm < count; ++mm) {
            int r = kidx[mm];
            float4 bi = s_obx[r]; float ai = s_oar[r];   // uniform broadcast reads
            float ltx = fmaxf(bi.x, bj.x), lty = fmaxf(bi.y, bj.y);
            float rbx = fminf(bi.z, bj.z), rby = fminf(bi.w, bj.w);
            float w = fmaxf(__fsub_rn(rbx, ltx), 0.f);
            float h = fmaxf(__fsub_rn(rby, lty), 0.f);
            float inter = __fmul_rn(w, h);
            float denom = __fadd_rn(__fsub_rn(__fadd_rn(ai, aj), inter), 1e-9f);
            sup0 = sup0 || (inter / denom > NMS_THRF);
        }
        uint64_t bm = __ballot(colv && sup0);

        // greedy over this chunk; kept row b's box comes from lane b via shfl
        int lim = V - (c << 6); if (lim > 64) lim = 64;
        for (int b = 0; b < lim; ++b) {
            if ((bm >> b) & 1) continue;
            int r = (c << 6) + b;
            if (lane == 0) kidx[count] = r;
            ++count;
            float bix1 = __shfl(bj.x, b), biy1 = __shfl(bj.y, b);
            float bix2 = __shfl(bj.z, b), biy2 = __shfl(bj.w, b);
            float ai   = __shfl(aj,   b);
            float ltx = fmaxf(bix1, bj.x), lty = fmaxf(biy1, bj.y);
            float rbx = fminf(bix2, bj.z), rby = fminf(biy2, bj.w);
            float w = fmaxf(__fsub_rn(rbx, ltx), 0.f);
            float h = fmaxf(__fsub_rn(rby, lty), 0.f);
            float inter = __fmul_rn(w, h);
            float denom = __fadd_rn(__fsub_rn(__fadd_rn(ai, aj), inter), 1e-9f);
            bool sup = colv && (jcol > r) && (inter / denom > NMS_THRF);
            bm |= __ballot(sup);
            if (count >= MAXOUT) break;
        }
    }

    float* ob = out;                          // [32*100*4]
    float* os = out + N_IMG * MAXOUT * 4;     // [32*100]
    float* ol = os + N_IMG * MAXOUT;          // [32*100] labels as float
    for (int mi = lane; mi < MAXOUT; mi += 64) {
        int o4 = (n * MAXOUT + mi) * 4;
        if (mi < count) {
            int i = kidx[mi];
            float4 b  = s_raw[i];
            float2 sl = s_sl[i];
            ob[o4 + 0] = b.x; ob[o4 + 1] = b.y; ob[o4 + 2] = b.z; ob[o4 + 3] = b.w;
            os[n * MAXOUT + mi] = sl.x;
            ol[n * MAXOUT + mi] = sl.y;
        } else {
            ob[o4 + 0] = 0.f; ob[o4 + 1] = 0.f; ob[o4 + 2] = 0.f; ob[o4 + 3] = 0.f;
            os[n * MAXOUT + mi] = 0.f;
            ol[n * MAXOUT + mi] = -1.f;
        }
    }
}

extern "C" void kernel_launch(void* const* d_in, const int* in_sizes, int n_in,
                              void* d_out, int out_size, void* d_ws, size_t ws_size,
                              hipStream_t stream)
{
    const float* cls0 = (const float*)d_in[0];
    const float* cls1 = (const float*)d_in[1];
    const float* cls2 = (const float*)d_in[2];
    const float* reg0 = (const float*)d_in[3];
    const float* reg1 = (const float*)d_in[4];
    const float* reg2 = (const float*)d_in[5];
    const float* obj0 = (const float*)d_in[6];
    const float* obj1 = (const float*)d_in[7];
    const float* obj2 = (const float*)d_in[8];

    uint64_t* keys = (uint64_t*)d_ws;     // 32*8400*8 B = 2.1 MB
    float* out = (float*)d_out;

    k_score<<<(N_IMG * P_TOT) / 64, 256, 0, stream>>>(
        cls0, cls1, cls2, obj0, obj1, obj2, keys);
    k_selnms<<<N_IMG, 1024, 0, stream>>>(keys, reg0, reg1, reg2, out);
}

// Round 18
// 67.923 us; speedup vs baseline: 1.0604x; 1.0604x over previous
//
#include <hip/hip_runtime.h>
#include <stdint.h>

#define N_IMG 32
#define P_TOT 8400
#define NCLS 80
#define NMS_PRE 1000
#define MAXOUT 100
#define SCORE_THRF 0.01f
#define NMS_THRF 0.65f
#define CAND_N 2048
#define NB 512          // histogram bins over dk>>17
#define BINBASE 8192    // valid masked scores [0.01,1.0] -> dk>>17 in [8255,8686]
#define TIE_EPS 0.05f   // sigmoid float-rounding tie window (validated R9/R10/R12, absmax 0)

// Level layout: p in [0,6400): 80x80 s=8 ; [6400,8000): 40x40 s=16 ; [8000,8400): 20x20 s=32

__device__ __forceinline__ float sigmoidf_(float x) { return 1.0f / (1.0f + expf(-x)); }

// ---------------- Kernel 1: scores -> sort keys (R12 exact — best measured) ----------------
__global__ __launch_bounds__(256) void k_score(
    const float* __restrict__ cls0, const float* __restrict__ cls1, const float* __restrict__ cls2,
    const float* __restrict__ obj0, const float* __restrict__ obj1, const float* __restrict__ obj2,
    uint64_t* __restrict__ keys)
{
    __shared__ float    pml[4][64];    // per-wave partial max logit
    __shared__ uint64_t part[4][64];   // per-wave partial packed sigmoid-argmax
    int lane = threadIdx.x & 63, wid = threadIdx.x >> 6;
    int a = blockIdx.x * 64 + lane;          // global anchor id, < 268800 exactly
    int n = a / P_TOT;
    int p = a - n * P_TOT;

    const float* cl; const float* ob; int HW, q;
    if (p < 6400)      { cl = cls0; ob = obj0; HW = 6400; q = p; }
    else if (p < 8000) { cl = cls1; ob = obj1; HW = 1600; q = p - 6400; }
    else               { cl = cls2; ob = obj2; HW = 400;  q = p - 8000; }

    const float* cbase = cl + (size_t)n * NCLS * HW + q;
    int c0 = wid * 20;

    float lg[20];
    #pragma unroll
    for (int i = 0; i < 20; ++i)
        lg[i] = cbase[(size_t)(c0 + i) * HW];
    __builtin_amdgcn_sched_group_barrier(0x20, 20, 0);   // 20 VMEM reads back-to-back

    float a0 = fmaxf(lg[0], lg[1]),  a1 = fmaxf(lg[2], lg[3]);
    float a2 = fmaxf(lg[4], lg[5]),  a3 = fmaxf(lg[6], lg[7]);
    float a4 = fmaxf(lg[8], lg[9]),  a5 = fmaxf(lg[10], lg[11]);
    float a6 = fmaxf(lg[12], lg[13]), a7 = fmaxf(lg[14], lg[15]);
    float a8 = fmaxf(lg[16], lg[17]), a9 = fmaxf(lg[18], lg[19]);
    float b0 = fmaxf(a0, a1), b1 = fmaxf(a2, a3), b2 = fmaxf(a4, a5);
    float b3 = fmaxf(a6, a7), b4 = fmaxf(a8, a9);
    float lmax = fmaxf(fmaxf(fmaxf(b0, b1), fmaxf(b2, b3)), b4);
    pml[wid][lane] = lmax;
    __syncthreads();

    float gmaxl = fmaxf(fmaxf(pml[0][lane], pml[1][lane]),
                        fmaxf(pml[2][lane], pml[3][lane]));
    float thr = gmaxl - TIE_EPS;
    uint64_t m = 0;
    #pragma unroll
    for (int i = 0; i < 20; ++i) {
        if (lg[i] >= thr) {
            float s = sigmoidf_(lg[i]);
            uint64_t pk = ((uint64_t)__float_as_uint(s) << 8) | (uint32_t)(79 - (c0 + i));
            m = m > pk ? m : pk;    // equal sig -> lower class wins (= jnp.argmax)
        }
    }
    part[wid][lane] = m;
    __syncthreads();

    if (wid == 0) {
        uint64_t m0 = part[0][lane], m1 = part[1][lane];
        uint64_t m2 = part[2][lane], m3 = part[3][lane];
        uint64_t ma = m0 > m1 ? m0 : m1, mb = m2 > m3 ? m2 : m3;
        uint64_t mm = ma > mb ? ma : mb;
        float best = __uint_as_float((uint32_t)(mm >> 8));   // = max_c sigmoid(cls_c), exact
        int bc = 79 - (int)(mm & 0xFFu);

        float so = sigmoidf_(ob[(size_t)n * HW + q]);
        float sc = __fmul_rn(best, so);
        float masked = (sc >= SCORE_THRF) ? sc : -1.0f;
        uint32_t u = __float_as_uint(masked);
        uint32_t ord = (u & 0x80000000u) ? ~u : (u | 0x80000000u);
        uint32_t dk = ~ord;                  // descending (valid => top bit 0)
        keys[a] = ((uint64_t)dk << 32) | (uint32_t)((p << 8) | bc);
    }
}

// ---------------- Kernel 2: counting-sort select + decode + NMS + output (R14 exact) ----------------
// LDS overlay: cand[2048] fixed; region B holds hist/base/fill/grouped during select,
// then obx/oar/raw/sl for NMS (grouped dead after ranking).
__global__ __launch_bounds__(1024) void k_selnms(
    const uint64_t* __restrict__ keys,
    const float* __restrict__ reg0, const float* __restrict__ reg1, const float* __restrict__ reg2,
    float* __restrict__ out)
{
    __shared__ __align__(16) char big[60416];
    __shared__ int   s_misc[2];
    __shared__ float fsh[17];
    __shared__ int   kidx[MAXOUT];

    uint64_t* cand    = (uint64_t*)big;                 // [2048]  (16384 B), whole kernel
    // select-phase overlays (big+16384 ..):
    uint32_t* hist    = (uint32_t*)(big + 16384);       // [512]
    uint32_t* base    = (uint32_t*)(big + 18432);       // [512]
    uint32_t* fill    = (uint32_t*)(big + 20480);       // [512]
    uint64_t* grouped = (uint64_t*)(big + 22528);       // [2048] (ends 38912)
    // nms-phase overlays (same region, after ranking):
    float4* s_obx = (float4*)(big + 16384);             // [1000] (16000)
    float*  s_oar = (float*) (big + 32384);             // [1000] ( 4000)
    float4* s_raw = (float4*)(big + 36384);             // [1000] (16000)
    float2* s_sl  = (float2*)(big + 52384);             // [1000] ( 8000) -> ends 60384

    int n = blockIdx.x, tid = threadIdx.x;

    if (tid < NB) { hist[tid] = 0; fill[tid] = 0; }
    for (int t = tid; t < CAND_N; t += 1024) cand[t] = ~0ull;
    __syncthreads();

    // pass 1: histogram valid keys
    #pragma unroll
    for (int it = 0; it < 9; ++it) {
        int t = tid + it * 1024;
        if (t < P_TOT) {
            uint64_t k = keys[(size_t)n * P_TOT + t];
            uint32_t dk = (uint32_t)(k >> 32);
            if (!(dk & 0x80000000u)) atomicAdd(&hist[(dk >> 17) - BINBASE], 1u);
        }
    }
    __syncthreads();

    // wave-0 prefix over 512 bins: per-bin exclusive base, total, cutoff bin
    if (tid < 64) {
        uint32_t c[8]; uint32_t s = 0;
        #pragma unroll
        for (int i = 0; i < 8; ++i) { c[i] = hist[tid * 8 + i]; s += c[i]; }
        uint32_t inc = s;
        #pragma unroll
        for (int o = 1; o < 64; o <<= 1) {
            uint32_t v = __shfl_up(inc, o);
            if (tid >= o) inc += v;
        }
        uint32_t excl = inc - s;
        uint32_t b = excl;
        #pragma unroll
        for (int i = 0; i < 8; ++i) { base[tid * 8 + i] = b; b += c[i]; }
        uint32_t total = __shfl(inc, 63);
        uint32_t target = total < (uint32_t)NMS_PRE ? total : (uint32_t)NMS_PRE;
        uint32_t cum = excl; int found = 0x7fffffff;
        #pragma unroll
        for (int i = 0; i < 8; ++i) {
            cum += c[i];
            if (found == 0x7fffffff && cum >= target && target > 0) found = tid * 8 + i;
        }
        #pragma unroll
        for (int o = 32; o > 0; o >>= 1) { int f = __shfl_xor(found, o); found = f < found ? f : found; }
        if (tid == 0) { s_misc[0] = (total > 0) ? found : -1; s_misc[1] = (int)target; }
    }
    __syncthreads();
    int Bcut = s_misc[0];

    // pass 2: scatter candidates (bins <= Bcut) into bin-grouped order (keys L2-warm)
    #pragma unroll
    for (int it = 0; it < 9; ++it) {
        int t = tid + it * 1024;
        if (t < P_TOT) {
            uint64_t k = keys[(size_t)n * P_TOT + t];
            uint32_t dk = (uint32_t)(k >> 32);
            if (!(dk & 0x80000000u)) {
                int bin = (int)((dk >> 17) - BINBASE);
                if (bin <= Bcut) {
                    uint32_t pos = base[bin] + atomicAdd(&fill[bin], 1u);
                    if (pos < CAND_N) grouped[pos] = k;
                }
            }
        }
    }
    __syncthreads();

    // exact rank within bin (keys unique -> total order identical to full sort)
    int ccnt = 0;
    if (Bcut >= 0) {
        uint32_t cc = base[Bcut] + hist[Bcut];
        ccnt = cc < (uint32_t)CAND_N ? (int)cc : CAND_N;
    }
    for (int s = tid; s < ccnt; s += 1024) {
        uint64_t k = grouped[s];
        uint32_t dk = (uint32_t)(k >> 32);
        int bin = (int)((dk >> 17) - BINBASE);
        uint32_t b0 = base[bin];
        uint32_t e0 = b0 + hist[bin]; if (e0 > (uint32_t)CAND_N) e0 = CAND_N;
        uint32_t r = b0;
        for (uint32_t t = b0; t < e0; ++t) r += (grouped[t] < k) ? 1u : 0u;
        if (r < (uint32_t)CAND_N) cand[r] = k;
    }
    int V = s_misc[1];
    __syncthreads();          // ranking done; hist/base/fill/grouped dead below

    // decode top-1000 from cand (LDS) exactly like reference; 1 anchor per thread
    float4 bx = make_float4(0.f, 0.f, 0.f, 0.f);
    float scm = -1.0f, labf = 0.f, m = 0.f;
    if (tid < NMS_PRE) {
        uint64_t key = cand[tid];
        uint32_t dk = (uint32_t)(key >> 32);
        if (!(dk & 0x80000000u)) {
            uint32_t low = (uint32_t)key;
            int lab = (int)(low & 0xFFu);
            int p   = (int)(low >> 8);
            uint32_t ord = ~dk;
            scm = __uint_as_float(ord ^ 0x80000000u);   // valid => positive float

            const float* rg; int HW, q, W; float s;
            if (p < 6400)      { rg = reg0; HW = 6400; q = p;        W = 80; s = 8.f; }
            else if (p < 8000) { rg = reg1; HW = 1600; q = p - 6400; W = 40; s = 16.f; }
            else               { rg = reg2; HW = 400;  q = p - 8000; W = 20; s = 32.f; }

            float px = (float)(q % W) * s;   // exact
            float py = (float)(q / W) * s;   // exact
            const float* rb = rg + (size_t)n * 4 * HW + q;
            float dx = rb[0], dy = rb[HW], dw = rb[2 * HW], dh = rb[3 * HW];
            float cx = __fadd_rn(__fmul_rn(dx, s), px);
            float cy = __fadd_rn(__fmul_rn(dy, s), py);
            float hw = __fmul_rn(__fmul_rn(expf(dw), s), 0.5f);
            float hh = __fmul_rn(__fmul_rn(expf(dh), s), 0.5f);
            bx.x = __fsub_rn(cx, hw); bx.y = __fsub_rn(cy, hh);
            bx.z = __fadd_rn(cx, hw); bx.w = __fadd_rn(cy, hh);
            labf = (float)lab;
            m = fmaxf(fmaxf(fabsf(bx.x), fabsf(bx.y)), fmaxf(fabsf(bx.z), fabsf(bx.w)));
        }
    }

    // gmax = max|b| over the 1000 gathered boxes (16-wave reduce)
    #pragma unroll
    for (int o = 32; o > 0; o >>= 1) m = fmaxf(m, __shfl_xor(m, o));
    if ((tid & 63) == 0) fsh[tid >> 6] = m;
    __syncthreads();
    if (tid == 0) {
        float g = fsh[0];
        #pragma unroll
        for (int w = 1; w < 16; ++w) g = fmaxf(g, fsh[w]);
        fsh[16] = g;
    }
    __syncthreads();
    float gmax = fsh[16];

    // stage NMS arrays (overlays dead select region; cand region untouched until here)
    if (tid < NMS_PRE) {
        float off = __fmul_rn(labf, __fadd_rn(gmax, 1.0f)); // lab * (max|b| + 1)
        float x1 = __fadd_rn(bx.x, off), y1 = __fadd_rn(bx.y, off);
        float x2 = __fadd_rn(bx.z, off), y2 = __fadd_rn(bx.w, off);
        s_obx[tid] = make_float4(x1, y1, x2, y2);
        s_oar[tid] = __fmul_rn(__fsub_rn(x2, x1), __fsub_rn(y2, y1));
        s_raw[tid] = bx;
        s_sl[tid]  = make_float2(scm, labf);
    }
    __syncthreads();
    if (tid >= 64) return;      // wave 0 finishes alone

    // ---- greedy NMS: lanes = kept boxes; candidates serial with LDS-broadcast prefetch ----
    int lane = tid;
    int count = 0;
    float k1x1 = 0.f, k1y1 = 0.f, k1x2 = 0.f, k1y2 = 0.f, k1a = 0.f;  // kept[lane]
    float k2x1 = 0.f, k2y1 = 0.f, k2x2 = 0.f, k2y2 = 0.f, k2a = 0.f;  // kept[lane+64]

    float4 nb = s_obx[0]; float na = s_oar[0];
    for (int i = 0; i < V && count < MAXOUT; ++i) {
        float4 cb = nb; float ca = na;
        int ip = (i + 1 < V) ? i + 1 : i;
        nb = s_obx[ip]; na = s_oar[ip];     // prefetch next candidate (indep of decision)

        bool sup = false;
        int c1 = count < 64 ? count : 64;
        if (lane < c1) {
            float ltx = fmaxf(k1x1, cb.x), lty = fmaxf(k1y1, cb.y);
            float rbx = fminf(k1x2, cb.z), rby = fminf(k1y2, cb.w);
            float w = fmaxf(__fsub_rn(rbx, ltx), 0.f);
            float h = fmaxf(__fsub_rn(rby, lty), 0.f);
            float inter = __fmul_rn(w, h);
            float denom = __fadd_rn(__fsub_rn(__fadd_rn(k1a, ca), inter), 1e-9f);
            sup = (inter / denom > NMS_THRF);
        }
        if (count > 64 && lane < count - 64) {
            float ltx = fmaxf(k2x1, cb.x), lty = fmaxf(k2y1, cb.y);
            float rbx = fminf(k2x2, cb.z), rby = fminf(k2y2, cb.w);
            float w = fmaxf(__fsub_rn(rbx, ltx), 0.f);
            float h = fmaxf(__fsub_rn(rby, lty), 0.f);
            float inter = __fmul_rn(w, h);
            float denom = __fadd_rn(__fsub_rn(__fadd_rn(k2a, ca), inter), 1e-9f);
            sup = sup || (inter / denom > NMS_THRF);
        }
        if (__ballot(sup) == 0ull) {
            if (lane == count)      { k1x1 = cb.x; k1y1 = cb.y; k1x2 = cb.z; k1y2 = cb.w; k1a = ca; }
            if (lane + 64 == count) { k2x1 = cb.x; k2y1 = cb.y; k2x2 = cb.z; k2y2 = cb.w; k2a = ca; }
            if (lane == 0) kidx[count] = i;
            ++count;
        }
    }

    float* ob = out;                          // [32*100*4]
    float* os = out + N_IMG * MAXOUT * 4;     // [32*100]
    float* ol = os + N_IMG * MAXOUT;          // [32*100] labels as float
    for (int mi = lane; mi < MAXOUT; mi += 64) {
        int o4 = (n * MAXOUT + mi) * 4;
        if (mi < count) {
            int i = kidx[mi];
            float4 b  = s_raw[i];
            float2 sl = s_sl[i];
            ob[o4 + 0] = b.x; ob[o4 + 1] = b.y; ob[o4 + 2] = b.z; ob[o4 + 3] = b.w;
            os[n * MAXOUT + mi] = sl.x;
            ol[n * MAXOUT + mi] = sl.y;
        } else {
            ob[o4 + 0] = 0.f; ob[o4 + 1] = 0.f; ob[o4 + 2] = 0.f; ob[o4 + 3] = 0.f;
            os[n * MAXOUT + mi] = 0.f;
            ol[n * MAXOUT + mi] = -1.f;
        }
    }
}

extern "C" void kernel_launch(void* const* d_in, const int* in_sizes, int n_in,
                              void* d_out, int out_size, void* d_ws, size_t ws_size,
                              hipStream_t stream)
{
    const float* cls0 = (const float*)d_in[0];
    const float* cls1 = (const float*)d_in[1];
    const float* cls2 = (const float*)d_in[2];
    const float* reg0 = (const float*)d_in[3];
    const float* reg1 = (const float*)d_in[4];
    const float* reg2 = (const float*)d_in[5];
    const float* obj0 = (const float*)d_in[6];
    const float* obj1 = (const float*)d_in[7];
    const float* obj2 = (const float*)d_in[8];

    uint64_t* keys = (uint64_t*)d_ws;     // 32*8400*8 B = 2.1 MB
    float* out = (float*)d_out;

    k_score<<<(N_IMG * P_TOT) / 64, 256, 0, stream>>>(
        cls0, cls1, cls2, obj0, obj1, obj2, keys);
    k_selnms<<<N_IMG, 1024, 0, stream>>>(keys, reg0, reg1, reg2, out);
}